// Round 1
// baseline (618.028 us; speedup 1.0000x reference)
//
#include <hip/hip_runtime.h>
#include <hip/hip_cooperative_groups.h>

namespace cg = cooperative_groups;

// Problem constants (from reference)
#define D_MODEL 1024
#define NB      8                        // batch N
#define SLEN    4096                     // sequence length S
#define D4      (D_MODEL / 4)            // 256 float4 per row
#define GROUPS  128                      // partial-sum groups per batch
#define ROWS_PER_GROUP (SLEN / GROUPS)   // 32 rows per block in phase 1
#define NBLOCKS (NB * GROUPS)            // 1024 blocks = 4 per CU (co-resident)

// y[n][i] = sum_j x[n][j] * W[i][j] + bias_scale * b[i], for one column i.
// 256 threads: thread t owns exactly one float4 of row i (D4 == 256).
// Two-level reduction: 64-lane shuffle, then 4-wave LDS combine.
__device__ __forceinline__ void gemv_col(
    const float4* __restrict__ X,     // [NB][D4]
    const float*  __restrict__ W,     // [D][D], row i = output i
    const float*  __restrict__ bvec,  // [D]
    float* __restrict__ Y,            // [NB][D_MODEL]
    float bias_scale, int i, int t, float (*red)[NB])
{
    const float4 w = ((const float4*)(W + (size_t)i * D_MODEL))[t];
    float acc[NB];
#pragma unroll
    for (int n = 0; n < NB; ++n) {
        float4 x = X[n * D4 + t];
        acc[n] = w.x * x.x + w.y * x.y + w.z * x.z + w.w * x.w;
    }
    const int lane = t & 63;
    const int wv   = t >> 6;
#pragma unroll
    for (int n = 0; n < NB; ++n) {
#pragma unroll
        for (int off = 32; off > 0; off >>= 1)
            acc[n] += __shfl_down(acc[n], off);
    }
    if (lane == 0) {
#pragma unroll
        for (int n = 0; n < NB; ++n) red[wv][n] = acc[n];
    }
    __syncthreads();
    if (t < NB)
        Y[(size_t)t * D_MODEL + i] =
            red[0][t] + red[1][t] + red[2][t] + red[3][t] + bias_scale * bvec[i];
}

// Single cooperative kernel: softmax over a size-1 axis == 1.0, so
//   out = ((sum_s V[n,s,:]) @ Wv.T + S*bv) @ Wo.T + bo
// Phase 1: atomic-free partial column sums of V (1024 blocks, coalesced 4 KiB rows)
// Phase 2: reduce 128 partials/batch -> Vsum (blocks 0..7, L2-resident)
// Phase 3: vproj = Vsum @ Wv.T + S*bv   (block i -> column i)
// Phase 4: out   = vproj @ Wo.T + bo
__global__ __launch_bounds__(256, 4) void fused_kernel(
    const float* __restrict__ V,
    const float* __restrict__ Wv, const float* __restrict__ bv,
    const float* __restrict__ Wo, const float* __restrict__ bo,
    float* __restrict__ out,
    float4* __restrict__ partials,   // [NBLOCKS][D4]
    float4* __restrict__ Vsum,       // [NB][D4]
    float4* __restrict__ vproj)      // [NB][D4]
{
    cg::grid_group grid = cg::this_grid();
    const int b = blockIdx.x;
    const int t = threadIdx.x;
    __shared__ float red[4][NB];

    // ---- Phase 1: partial column sums of V ----
    {
        const int n = b >> 7;            // b / GROUPS
        const int g = b & (GROUPS - 1);
        const float4* Vb = (const float4*)(V + (size_t)n * SLEN * D_MODEL);
        const size_t base = (size_t)g * ROWS_PER_GROUP * D4 + t;
        float4 acc = make_float4(0.f, 0.f, 0.f, 0.f);
#pragma unroll 8
        for (int r = 0; r < ROWS_PER_GROUP; ++r) {
            float4 x = Vb[base + (size_t)r * D4];
            acc.x += x.x; acc.y += x.y; acc.z += x.z; acc.w += x.w;
        }
        partials[(size_t)b * D4 + t] = acc;
    }
    grid.sync();

    // ---- Phase 2: reduce partials -> Vsum (blocks 0..7, one per batch) ----
    if (b < NB) {
        float4 acc = make_float4(0.f, 0.f, 0.f, 0.f);
#pragma unroll 8
        for (int g = 0; g < GROUPS; ++g) {
            float4 x = partials[((size_t)b * GROUPS + g) * D4 + t];
            acc.x += x.x; acc.y += x.y; acc.z += x.z; acc.w += x.w;
        }
        Vsum[b * D4 + t] = acc;
    }
    grid.sync();

    // ---- Phase 3: vproj = Vsum @ Wv.T + SLEN * bv ----
    gemv_col(Vsum, Wv, bv, (float*)vproj, (float)SLEN, b, t, red);
    grid.sync();

    // ---- Phase 4: out = vproj @ Wo.T + bo ----
    gemv_col(vproj, Wo, bo, out, 1.0f, b, t, red);
}

extern "C" void kernel_launch(void* const* d_in, const int* in_sizes, int n_in,
                              void* d_out, int out_size, void* d_ws, size_t ws_size,
                              hipStream_t stream) {
    // Input order: Q, K, V, Wq, bq, Wk, bk, Wv, bv, Wo, bo
    // Q/K/Wq/bq/Wk/bk are dead (softmax over size-1 axis == 1).
    const float* V  = (const float*)d_in[2];
    const float* Wv = (const float*)d_in[7];
    const float* bv = (const float*)d_in[8];
    const float* Wo = (const float*)d_in[9];
    const float* bo = (const float*)d_in[10];
    float* out = (float*)d_out;

    // Workspace: partials [NBLOCKS][D4] f4 (4 MiB), Vsum [NB][D4], vproj [NB][D4]
    float4* partials = (float4*)d_ws;
    float4* Vsum     = partials + (size_t)NBLOCKS * D4;
    float4* vproj    = Vsum + NB * D4;

    void* args[] = {(void*)&V,  (void*)&Wv, (void*)&bv, (void*)&Wo, (void*)&bo,
                    (void*)&out, (void*)&partials, (void*)&Vsum, (void*)&vproj};
    hipLaunchCooperativeKernel((const void*)fused_kernel, dim3(NBLOCKS),
                               dim3(256), args, 0, stream);
}

// Round 2
// 284.236 us; speedup vs baseline: 2.1743x; 2.1743x over previous
//
#include <hip/hip_runtime.h>

// Problem constants (from reference)
#define D_MODEL 1024
#define NB      8                       // batch N
#define SLEN    4096                    // sequence length S
#define D4      (D_MODEL / 4)           // 256 float4 per row
#define GROUPS  128                     // partial-sum groups per batch
#define ROWS_PER_GROUP (SLEN / GROUPS)  // 32 rows per block in phase 1
#define NBLOCKS (NB * GROUPS)           // 1024 blocks = 4 per CU

// Phase 1: atomic-free partial column sums of V.
// Block b = (n, g): sums 32 full rows, thread t owns float4 column t.
// Perfectly coalesced 4 KiB-wide row reads; writes a private 4 KiB slice.
// 1024 blocks = 4/CU = 16 waves/CU for HBM latency hiding.
__global__ __launch_bounds__(256) void vsum_partial_kernel(
    const float* __restrict__ V, float4* __restrict__ partials) {
    const int b = blockIdx.x;
    const int t = threadIdx.x;
    const int n = b >> 7;               // b / GROUPS
    const int g = b & (GROUPS - 1);

    const float4* Vb = (const float4*)(V + (size_t)n * SLEN * D_MODEL);
    const size_t base = (size_t)g * ROWS_PER_GROUP * D4 + t;

    float4 acc = make_float4(0.f, 0.f, 0.f, 0.f);
#pragma unroll 8
    for (int r = 0; r < ROWS_PER_GROUP; ++r) {
        float4 x = Vb[base + (size_t)r * D4];
        acc.x += x.x; acc.y += x.y; acc.z += x.z; acc.w += x.w;
    }
    partials[(size_t)b * D4 + t] = acc;
}

// Phase 2: reduce 128 partials per batch -> Vsum. 8 blocks (one per batch),
// thread t owns float4 column t; 128 independent 16 B loads, all L2-resident
// (4 MiB total).
__global__ __launch_bounds__(256) void vsum_reduce_kernel(
    const float4* __restrict__ partials, float4* __restrict__ Vsum) {
    const int n = blockIdx.x;
    const int t = threadIdx.x;
    float4 acc = make_float4(0.f, 0.f, 0.f, 0.f);
#pragma unroll 8
    for (int g = 0; g < GROUPS; ++g) {
        float4 x = partials[((size_t)n * GROUPS + g) * D4 + t];
        acc.x += x.x; acc.y += x.y; acc.z += x.z; acc.w += x.w;
    }
    Vsum[(size_t)n * D4 + t] = acc;
}

// Phases 3/4: y[n][i] = sum_j x[n][j]*W[i][j] + bias_scale*b[i].
// 256 blocks x 256 threads; each wave handles one output column i for all 8
// batches (W row read once). float4 loads, shuffle reduction.
__global__ __launch_bounds__(256) void gemv8_kernel(
    const float4* __restrict__ X,    // [NB][D4]
    const float*  __restrict__ W,    // [D][D], row i = output i
    const float*  __restrict__ bvec, // [D]
    float* __restrict__ Y,           // [NB][D]
    float bias_scale) {
    const int t    = threadIdx.x;
    const int wv   = t >> 6;
    const int lane = t & 63;
    const int i    = blockIdx.x * 4 + wv;

    const float4* Wr = (const float4*)(W + (size_t)i * D_MODEL);

    float acc[NB];
#pragma unroll
    for (int n = 0; n < NB; ++n) acc[n] = 0.f;

#pragma unroll
    for (int g = lane; g < D4; g += 64) {   // 4 iterations
        float4 w = Wr[g];
#pragma unroll
        for (int n = 0; n < NB; ++n) {
            float4 x = X[n * D4 + g];
            acc[n] += w.x * x.x + w.y * x.y + w.z * x.z + w.w * x.w;
        }
    }

#pragma unroll
    for (int n = 0; n < NB; ++n) {
        float v = acc[n];
#pragma unroll
        for (int off = 32; off > 0; off >>= 1) v += __shfl_down(v, off);
        if (lane == 0) Y[(size_t)n * D_MODEL + i] = v + bias_scale * bvec[i];
    }
}

extern "C" void kernel_launch(void* const* d_in, const int* in_sizes, int n_in,
                              void* d_out, int out_size, void* d_ws, size_t ws_size,
                              hipStream_t stream) {
    // Input order: Q, K, V, Wq, bq, Wk, bk, Wv, bv, Wo, bo
    // softmax over a size-1 axis == 1.0, so Q/K/Wq/bq/Wk/bk are dead:
    //   out = ((sum_s V[n,s,:]) @ Wv.T + S*bv) @ Wo.T + bo
    const float* V  = (const float*)d_in[2];
    const float* Wv = (const float*)d_in[7];
    const float* bv = (const float*)d_in[8];
    const float* Wo = (const float*)d_in[9];
    const float* bo = (const float*)d_in[10];
    float* out = (float*)d_out;

    // Workspace: partials [NBLOCKS][D4] f4 (4 MiB), Vsum [NB][D4], vproj [NB][D4]
    float4* partials = (float4*)d_ws;
    float4* Vsum     = partials + (size_t)NBLOCKS * D4;
    float4* vproj    = Vsum + NB * D4;

    vsum_partial_kernel<<<NBLOCKS, 256, 0, stream>>>(V, partials);
    vsum_reduce_kernel<<<NB, 256, 0, stream>>>(partials, Vsum);
    gemv8_kernel<<<D_MODEL / 4, 256, 0, stream>>>(Vsum, Wv, bv, (float*)vproj,
                                                  (float)SLEN);
    gemv8_kernel<<<D_MODEL / 4, 256, 0, stream>>>(vproj, Wo, bo, out, 1.0f);
}

// Round 3
// 283.153 us; speedup vs baseline: 2.1827x; 1.0038x over previous
//
#include <hip/hip_runtime.h>

// Problem constants (from reference)
#define D_MODEL 1024
#define NB      8                       // batch N
#define SLEN    4096                    // sequence length S
#define D4      (D_MODEL / 4)           // 256 float4 per row
#define GROUPS  256                     // partial-sum groups per batch
#define ROWS_PER_GROUP (SLEN / GROUPS)  // 16 rows per block in phase 1
#define NBLOCKS (NB * GROUPS)           // 2048 blocks = 8 per CU (max occupancy)

// Phase 1: atomic-free partial column sums of V.
// Block b = (n, g): sums 16 full rows, thread t owns float4 column t.
// Perfectly coalesced 4 KiB-wide row reads; writes a private 4 KiB slice.
// 2048 blocks = 8/CU = 32 waves/CU -> max latency hiding for the HBM stream.
__global__ __launch_bounds__(256) void vsum_partial_kernel(
    const float* __restrict__ V, float4* __restrict__ partials) {
    const int b = blockIdx.x;
    const int t = threadIdx.x;
    const int n = b >> 8;               // b / GROUPS
    const int g = b & (GROUPS - 1);

    const float4* Vb = (const float4*)(V + (size_t)n * SLEN * D_MODEL);
    const size_t base = (size_t)g * ROWS_PER_GROUP * D4 + t;

    float4 acc = make_float4(0.f, 0.f, 0.f, 0.f);
#pragma unroll 8
    for (int r = 0; r < ROWS_PER_GROUP; ++r) {
        float4 x = Vb[base + (size_t)r * D4];
        acc.x += x.x; acc.y += x.y; acc.z += x.z; acc.w += x.w;
    }
    partials[(size_t)b * D4 + t] = acc;
}

// Phase 2: reduce 256 partials per batch -> Vsum.
// 64 blocks = (n, c): batch n, 32-float4-column chunk c. Thread t owns
// column c*32+(t&31) and group-stride g0=(t>>5)..+8; shuffle-xor(32) then
// 4-wave LDS combine. Spreads the 8 MiB L2-resident read over 64 CUs.
__global__ __launch_bounds__(256) void vsum_reduce_kernel(
    const float4* __restrict__ partials, float4* __restrict__ Vsum) {
    const int b = blockIdx.x;
    const int n = b >> 3;
    const int c = b & 7;
    const int t = threadIdx.x;
    const int col = (c << 5) + (t & 31);   // float4 column 0..255
    const int g0  = t >> 5;                // 0..7

    const float4* P = partials + (size_t)n * GROUPS * D4;
    float4 acc = make_float4(0.f, 0.f, 0.f, 0.f);
#pragma unroll 8
    for (int k = 0; k < GROUPS / 8; ++k) {   // 32 iterations
        float4 x = P[(size_t)(g0 + (k << 3)) * D4 + col];
        acc.x += x.x; acc.y += x.y; acc.z += x.z; acc.w += x.w;
    }
    // lanes l and l^32 share col (g0 differs by 1): pairwise reduce.
    acc.x += __shfl_xor(acc.x, 32);
    acc.y += __shfl_xor(acc.y, 32);
    acc.z += __shfl_xor(acc.z, 32);
    acc.w += __shfl_xor(acc.w, 32);

    __shared__ float4 red[4][32];
    const int lane = t & 63;
    const int wv   = t >> 6;
    if (lane < 32) red[wv][lane] = acc;
    __syncthreads();
    if (t < 32) {
        float4 a = red[0][t], b2 = red[1][t], c2 = red[2][t], d = red[3][t];
        float4 r;
        r.x = a.x + b2.x + c2.x + d.x;
        r.y = a.y + b2.y + c2.y + d.y;
        r.z = a.z + b2.z + c2.z + d.z;
        r.w = a.w + b2.w + c2.w + d.w;
        Vsum[(size_t)n * D4 + (c << 5) + t] = r;
    }
}

// Phases 3/4: y[n][i] = sum_j x[n][j]*W[i][j] + bias_scale*b[i].
// 256 blocks x 256 threads; each wave handles one output column i for all 8
// batches. W row prefetched as 4 independent float4 loads (MLP at 1 wave/SIMD
// occupancy), X is L2-resident; shuffle reduction.
__global__ __launch_bounds__(256) void gemv8_kernel(
    const float4* __restrict__ X,    // [NB][D4]
    const float*  __restrict__ W,    // [D][D], row i = output i
    const float*  __restrict__ bvec, // [D]
    float* __restrict__ Y,           // [NB][D]
    float bias_scale) {
    const int t    = threadIdx.x;
    const int wv   = t >> 6;
    const int lane = t & 63;
    const int i    = blockIdx.x * 4 + wv;

    const float4* Wr = (const float4*)(W + (size_t)i * D_MODEL);

    // 4 independent W loads issued upfront.
    const float4 w0 = Wr[lane];
    const float4 w1 = Wr[lane + 64];
    const float4 w2 = Wr[lane + 128];
    const float4 w3 = Wr[lane + 192];

    float acc[NB];
#pragma unroll
    for (int n = 0; n < NB; ++n) {
        const float4 x0 = X[n * D4 + lane];
        const float4 x1 = X[n * D4 + lane + 64];
        const float4 x2 = X[n * D4 + lane + 128];
        const float4 x3 = X[n * D4 + lane + 192];
        acc[n] = w0.x * x0.x + w0.y * x0.y + w0.z * x0.z + w0.w * x0.w
               + w1.x * x1.x + w1.y * x1.y + w1.z * x1.z + w1.w * x1.w
               + w2.x * x2.x + w2.y * x2.y + w2.z * x2.z + w2.w * x2.w
               + w3.x * x3.x + w3.y * x3.y + w3.z * x3.z + w3.w * x3.w;
    }

#pragma unroll
    for (int n = 0; n < NB; ++n) {
        float v = acc[n];
#pragma unroll
        for (int off = 32; off > 0; off >>= 1) v += __shfl_down(v, off);
        if (lane == 0) Y[(size_t)n * D_MODEL + i] = v + bias_scale * bvec[i];
    }
}

extern "C" void kernel_launch(void* const* d_in, const int* in_sizes, int n_in,
                              void* d_out, int out_size, void* d_ws, size_t ws_size,
                              hipStream_t stream) {
    // Input order: Q, K, V, Wq, bq, Wk, bk, Wv, bv, Wo, bo
    // softmax over a size-1 axis == 1.0, so Q/K/Wq/bq/Wk/bk are dead:
    //   out = ((sum_s V[n,s,:]) @ Wv.T + S*bv) @ Wo.T + bo
    const float* V  = (const float*)d_in[2];
    const float* Wv = (const float*)d_in[7];
    const float* bv = (const float*)d_in[8];
    const float* Wo = (const float*)d_in[9];
    const float* bo = (const float*)d_in[10];
    float* out = (float*)d_out;

    // Workspace: partials [NBLOCKS][D4] f4 (8 MiB), Vsum [NB][D4], vproj [NB][D4]
    float4* partials = (float4*)d_ws;
    float4* Vsum     = partials + (size_t)NBLOCKS * D4;
    float4* vproj    = Vsum + NB * D4;

    vsum_partial_kernel<<<NBLOCKS, 256, 0, stream>>>(V, partials);
    vsum_reduce_kernel<<<64, 256, 0, stream>>>(partials, Vsum);
    gemv8_kernel<<<D_MODEL / 4, 256, 0, stream>>>(Vsum, Wv, bv, (float*)vproj,
                                                  (float)SLEN);
    gemv8_kernel<<<D_MODEL / 4, 256, 0, stream>>>(vproj, Wo, bo, out, 1.0f);
}